// Round 1
// baseline (703.341 us; speedup 1.0000x reference)
//
#include <hip/hip_runtime.h>
#include <math.h>

#define BB 16
#define CC 128
#define NN 2048
#define CQ 32   // C/4

// ---------------- workspace layout (floats) ----------------
// Q    : [B][32][N]    off 0           size 1,048,576
// V    : [B][128][N]   off 1,048,576   size 4,194,304
// XR   : [B][128][N]   off 5,242,880   size 4,194,304
// RM   : [B][N]        off 9,437,184   size 32,768
// RS   : [B][N]        off 9,469,952   size 32,768
// WT_T : [128][128]    off 9,502,720   size 16,384
// total 9,519,104 floats = 38.1 MB
#define OFF_Q   0
#define OFF_V   1048576
#define OFF_XR  5242880
#define OFF_RM  9437184
#define OFF_RS  9469952
#define OFF_WTT 9502720

// K0: transpose wt -> wt_t[c2][c]
__global__ void k_wtT(const float* __restrict__ wt, float* __restrict__ wt_t) {
    int idx = blockIdx.x * 256 + threadIdx.x;   // 16384 total
    int c = idx >> 7, c2 = idx & 127;
    wt_t[c2 * CC + c] = wt[c * CC + c2];
}

// K1: Q[b,d,n] = sum_c wq[d,c] x[b,c,n] ;  V[b,d,n] = sum_c wv[d,c] x[b,c,n] + bv[d]
__global__ __launch_bounds__(256) void k_proj(const float* __restrict__ x,
        const float* __restrict__ wq, const float* __restrict__ wv,
        const float* __restrict__ bv, float* __restrict__ Q, float* __restrict__ V) {
    __shared__ float xs[CC][68];   // 128 c x 64 n tile, stride 68 (16B aligned)
    int b  = blockIdx.x >> 5;          // 32 n-tiles per batch
    int n0 = (blockIdx.x & 31) << 6;
    int tid = threadIdx.x;
    const float* xb = x + b * CC * NN;
    for (int idx = tid; idx < CC * 64; idx += 256) {
        int c = idx >> 6, n = idx & 63;
        xs[c][n] = xb[c * NN + n0 + n];
    }
    __syncthreads();
    int q4 = (tid & 15) << 2;   // n offset within tile (float4)
    int g  = tid >> 4;          // 0..15 -> outputs d = g*10 .. g*10+9
    float acc[10][4];
    #pragma unroll
    for (int o = 0; o < 10; ++o)
        for (int j = 0; j < 4; ++j) acc[o][j] = 0.f;
    for (int c = 0; c < CC; ++c) {
        float4 xv = *(const float4*)&xs[c][q4];
        #pragma unroll
        for (int o = 0; o < 10; ++o) {
            int d = g * 10 + o;
            float w = (d < CQ) ? wq[d * CC + c] : wv[(d - CQ) * CC + c];
            acc[o][0] += w * xv.x; acc[o][1] += w * xv.y;
            acc[o][2] += w * xv.z; acc[o][3] += w * xv.w;
        }
    }
    int n = n0 + q4;
    #pragma unroll
    for (int o = 0; o < 10; ++o) {
        int d = g * 10 + o;
        if (d < CQ) {
            *(float4*)&Q[(b * CQ + d) * NN + n] =
                make_float4(acc[o][0], acc[o][1], acc[o][2], acc[o][3]);
        } else {
            int dv = d - CQ;
            float bb = bv[dv];
            *(float4*)&V[(b * CC + dv) * NN + n] =
                make_float4(acc[o][0] + bb, acc[o][1] + bb, acc[o][2] + bb, acc[o][3] + bb);
        }
    }
}

// K2: per-row online softmax stats over energy row n: e[n,m] = sum_d Q[d,n]Q[d,m]
__global__ __launch_bounds__(256) void k_rowstats(const float* __restrict__ Q,
        float* __restrict__ RM, float* __restrict__ RS) {
    __shared__ float Qm[64][40];
    __shared__ float Ms[256], Ss[256];
    int b  = blockIdx.x >> 6;          // 64 row-tiles of 32 per batch
    int n0 = (blockIdx.x & 63) << 5;
    int tid = threadIdx.x;
    int r = tid & 31, s = tid >> 5;    // row within tile, m-subgroup 0..7
    const float* Qb = Q + b * CQ * NN;
    float qr[CQ];
    #pragma unroll
    for (int d = 0; d < CQ; ++d) qr[d] = Qb[d * NN + n0 + r];
    float M = -1e30f, S = 0.f;
    for (int mt = 0; mt < NN; mt += 64) {
        __syncthreads();
        for (int idx = tid; idx < CQ * 64; idx += 256) {
            int d = idx >> 6, m = idx & 63;
            Qm[m][d] = Qb[d * NN + mt + m];
        }
        __syncthreads();
        #pragma unroll
        for (int j = 0; j < 8; ++j) {
            int m = s * 8 + j;
            float e = 0.f;
            #pragma unroll
            for (int d4 = 0; d4 < CQ; d4 += 4) {
                float4 kv = *(const float4*)&Qm[m][d4];
                e += qr[d4] * kv.x + qr[d4 + 1] * kv.y
                   + qr[d4 + 2] * kv.z + qr[d4 + 3] * kv.w;
            }
            if (e > M) { S *= __expf(M - e); M = e; }
            S += __expf(e - M);
        }
    }
    Ms[tid] = M; Ss[tid] = S;
    __syncthreads();
    if (tid < 32) {
        float Mr = -1e30f;
        #pragma unroll
        for (int s2 = 0; s2 < 8; ++s2) Mr = fmaxf(Mr, Ms[tid + 32 * s2]);
        float Sr = 0.f;
        #pragma unroll
        for (int s2 = 0; s2 < 8; ++s2) Sr += Ss[tid + 32 * s2] * __expf(Ms[tid + 32 * s2] - Mr);
        RM[b * NN + n0 + tid] = Mr;
        RS[b * NN + n0 + tid] = Sr;
    }
}

// K3: for m-tile: w[n,m] = exp(e[n,m]-RM[n])/RS[n]; colsum[m]+=w; xr[d,m]+=V[d,n]*w
//     XR[d,m] = xr / (1e-9 + colsum[m])
__global__ __launch_bounds__(256) void k_attn_pv(const float* __restrict__ Q,
        const float* __restrict__ V, const float* __restrict__ RM,
        const float* __restrict__ RS, float* __restrict__ XR) {
    __shared__ float Qn[64][40];
    __shared__ float Vs[64][132];
    __shared__ float Ws[64][68];
    __shared__ float rm_s[64], rsi_s[64];
    __shared__ float csred[4][64];
    int b  = blockIdx.x >> 5;          // 32 m-tiles per batch
    int m0 = (blockIdx.x & 31) << 6;
    int tid = threadIdx.x;
    int m = tid & 63, g = tid >> 6;    // g = 0..3
    const float* Qb = Q + b * CQ * NN;
    const float* Vb = V + b * CC * NN;
    float qm[CQ];
    #pragma unroll
    for (int d = 0; d < CQ; ++d) qm[d] = Qb[d * NN + m0 + m];
    float acc[32];
    #pragma unroll
    for (int i = 0; i < 32; ++i) acc[i] = 0.f;
    float cs = 0.f;
    for (int nt = 0; nt < NN; nt += 64) {
        __syncthreads();
        for (int idx = tid; idx < CQ * 64; idx += 256) {
            int d = idx >> 6, n = idx & 63;
            Qn[n][d] = Qb[d * NN + nt + n];
        }
        for (int idx = tid; idx < CC * 64; idx += 256) {
            int d = idx >> 6, n = idx & 63;
            Vs[n][d] = Vb[d * NN + nt + n];
        }
        if (tid < 64) {
            rm_s[tid]  = RM[b * NN + nt + tid];
            rsi_s[tid] = 1.f / RS[b * NN + nt + tid];
        }
        __syncthreads();
        // energies + attention weights for this thread's 16 n
        #pragma unroll
        for (int i = 0; i < 16; ++i) {
            int n = g * 16 + i;
            float e = 0.f;
            #pragma unroll
            for (int d4 = 0; d4 < CQ; d4 += 4) {
                float4 qv = *(const float4*)&Qn[n][d4];
                e += qv.x * qm[d4] + qv.y * qm[d4 + 1]
                   + qv.z * qm[d4 + 2] + qv.w * qm[d4 + 3];
            }
            float w = __expf(e - rm_s[n]) * rsi_s[n];
            cs += w;
            Ws[n][m] = w;
        }
        __syncthreads();
        // PV accumulate: this thread owns d in [g*32, g*32+32)
        #pragma unroll 4
        for (int n = 0; n < 64; ++n) {
            float wv = Ws[n][m];
            #pragma unroll
            for (int d4 = 0; d4 < 32; d4 += 4) {
                float4 vv = *(const float4*)&Vs[n][g * 32 + d4];
                acc[d4]     += vv.x * wv;
                acc[d4 + 1] += vv.y * wv;
                acc[d4 + 2] += vv.z * wv;
                acc[d4 + 3] += vv.w * wv;
            }
        }
    }
    __syncthreads();
    csred[g][m] = cs;
    __syncthreads();
    float cstot = csred[0][m] + csred[1][m] + csred[2][m] + csred[3][m];
    float inv = 1.f / (1e-9f + cstot);
    #pragma unroll
    for (int d = 0; d < 32; ++d) {
        XR[(b * CC + g * 32 + d) * NN + m0 + m] = acc[d] * inv;
    }
}

// K4: t = wt @ (x - XR) + bt ; BN eval + ReLU ; out = x + relu(t)
__global__ __launch_bounds__(256) void k_final(const float* __restrict__ x,
        const float* __restrict__ XR, const float* __restrict__ wt_t,
        const float* __restrict__ bt, const float* __restrict__ gamma,
        const float* __restrict__ beta, const float* __restrict__ bn_mean,
        const float* __restrict__ bn_var, float* __restrict__ out) {
    __shared__ float us[CC][68];
    int b  = blockIdx.x >> 5;
    int m0 = (blockIdx.x & 31) << 6;
    int tid = threadIdx.x;
    const float* xb  = x  + b * CC * NN;
    const float* xrb = XR + b * CC * NN;
    for (int idx = tid; idx < CC * 64; idx += 256) {
        int c = idx >> 6, n = idx & 63;
        us[c][n] = xb[c * NN + m0 + n] - xrb[c * NN + m0 + n];
    }
    __syncthreads();
    int c = tid & 127, h = tid >> 7;   // h = m-half
    float acc[32];
    #pragma unroll
    for (int j = 0; j < 32; ++j) acc[j] = 0.f;
    for (int c2 = 0; c2 < CC; ++c2) {
        float w = wt_t[c2 * CC + c];
        #pragma unroll
        for (int j4 = 0; j4 < 32; j4 += 4) {
            float4 uv = *(const float4*)&us[c2][h * 32 + j4];
            acc[j4]     += w * uv.x;
            acc[j4 + 1] += w * uv.y;
            acc[j4 + 2] += w * uv.z;
            acc[j4 + 3] += w * uv.w;
        }
    }
    float A  = gamma[c] * rsqrtf(bn_var[c] + 1e-5f);
    float Bc = beta[c] - bn_mean[c] * A;
    float tb = bt[c];
    __syncthreads();
    #pragma unroll
    for (int j = 0; j < 32; ++j) {
        float t = (acc[j] + tb) * A + Bc;
        us[c][h * 32 + j] = fmaxf(t, 0.f);
    }
    __syncthreads();
    for (int idx = tid; idx < CC * 64; idx += 256) {
        int cc = idx >> 6, n = idx & 63;
        out[(b * CC + cc) * NN + m0 + n] = xb[cc * NN + m0 + n] + us[cc][n];
    }
}

extern "C" void kernel_launch(void* const* d_in, const int* in_sizes, int n_in,
                              void* d_out, int out_size, void* d_ws, size_t ws_size,
                              hipStream_t stream) {
    const float* x       = (const float*)d_in[0];
    const float* wq      = (const float*)d_in[1];
    const float* wv      = (const float*)d_in[2];
    const float* bv      = (const float*)d_in[3];
    const float* wt      = (const float*)d_in[4];
    const float* bt      = (const float*)d_in[5];
    const float* gamma   = (const float*)d_in[6];
    const float* beta    = (const float*)d_in[7];
    const float* bn_mean = (const float*)d_in[8];
    const float* bn_var  = (const float*)d_in[9];
    float* out = (float*)d_out;
    float* ws  = (float*)d_ws;

    float* Q    = ws + OFF_Q;
    float* V    = ws + OFF_V;
    float* XR   = ws + OFF_XR;
    float* RM   = ws + OFF_RM;
    float* RS   = ws + OFF_RS;
    float* WT_T = ws + OFF_WTT;

    k_wtT<<<64, 256, 0, stream>>>(wt, WT_T);
    k_proj<<<BB * 32, 256, 0, stream>>>(x, wq, wv, bv, Q, V);
    k_rowstats<<<BB * 64, 256, 0, stream>>>(Q, RM, RS);
    k_attn_pv<<<BB * 32, 256, 0, stream>>>(Q, V, RM, RS, XR);
    k_final<<<BB * 32, 256, 0, stream>>>(x, XR, WT_T, bt, gamma, beta, bn_mean, bn_var, out);
}

// Round 2
// 177.539 us; speedup vs baseline: 3.9616x; 3.9616x over previous
//
#include <hip/hip_runtime.h>
#include <math.h>

#define BB 16
#define CC 128
#define NN 2048
#define CQ 32   // C/4

typedef __attribute__((ext_vector_type(8))) short bf16x8;
typedef __attribute__((ext_vector_type(4))) float f32x4;

__device__ __forceinline__ ushort f2b(float f) {
    union { float f; unsigned u; } v; v.f = f;
    unsigned r = v.u + 0x7fffu + ((v.u >> 16) & 1u);
    return (ushort)(r >> 16);
}

// ---------------- workspace layout (float granularity offsets) ----------------
// Qt  : bf16 [B][N][32]   off 0         (1,048,576 shorts = 524,288 floats)
// Vb  : bf16 [B][128][N]  off 524,288   (4,194,304 shorts = 2,097,152 floats)
// XR  : f32  [B][128][N]  off 2,621,440 (4,194,304 floats)
// RM  : f32  [B][N]       off 6,815,744
// RS  : f32  [B][N]       off 6,848,512
// WT_T: f32  [128][128]   off 6,881,280
#define OFF_VB  524288
#define OFF_XR  2621440
#define OFF_RM  6815744
#define OFF_RS  6848512
#define OFF_WTT 6881280

// K0: transpose wt -> wt_t[c2][c]
__global__ void k_wtT(const float* __restrict__ wt, float* __restrict__ wt_t) {
    int idx = blockIdx.x * 256 + threadIdx.x;
    int c = idx >> 7, c2 = idx & 127;
    wt_t[c2 * CC + c] = wt[c * CC + c2];
}

// K1: Qt[b,n,d] = sum_c wq[d,c] x[b,c,n] (bf16, transposed layout)
//     Vb[b,d,n] = sum_c wv[d,c] x[b,c,n] + bv[d] (bf16)
__global__ __launch_bounds__(256) void k_proj(const float* __restrict__ x,
        const float* __restrict__ wq, const float* __restrict__ wv,
        const float* __restrict__ bv, ushort* __restrict__ Qt, ushort* __restrict__ Vb) {
    __shared__ float xs[CC][68];
    __shared__ ushort QtS[64][36];   // [n][d] bf16, row stride 72B (8B aligned)
    int b  = blockIdx.x >> 5;
    int n0 = (blockIdx.x & 31) << 6;
    int tid = threadIdx.x;
    const float* xb = x + (size_t)b * CC * NN;
    for (int idx = tid; idx < CC * 64; idx += 256) {
        int c = idx >> 6, n = idx & 63;
        xs[c][n] = xb[c * NN + n0 + n];
    }
    __syncthreads();
    int q4 = (tid & 15) << 2;
    int g  = tid >> 4;
    float acc[10][4];
    #pragma unroll
    for (int o = 0; o < 10; ++o)
        for (int j = 0; j < 4; ++j) acc[o][j] = 0.f;
    for (int c = 0; c < CC; ++c) {
        float4 xv = *(const float4*)&xs[c][q4];
        #pragma unroll
        for (int o = 0; o < 10; ++o) {
            int d = g * 10 + o;
            float w = (d < CQ) ? wq[d * CC + c] : wv[(d - CQ) * CC + c];
            acc[o][0] += w * xv.x; acc[o][1] += w * xv.y;
            acc[o][2] += w * xv.z; acc[o][3] += w * xv.w;
        }
    }
    #pragma unroll
    for (int o = 0; o < 10; ++o) {
        int d = g * 10 + o;
        if (d < CQ) {
            #pragma unroll
            for (int j = 0; j < 4; ++j) QtS[q4 + j][d] = f2b(acc[o][j]);
        } else {
            int dv = d - CQ;
            float bb = bv[dv];
            ushort4 p = make_ushort4(f2b(acc[o][0] + bb), f2b(acc[o][1] + bb),
                                     f2b(acc[o][2] + bb), f2b(acc[o][3] + bb));
            *(ushort4*)&Vb[(size_t)(b * CC + dv) * NN + n0 + q4] = p;
        }
    }
    __syncthreads();
    {
        int r = tid >> 2, c = tid & 3;
        uint2 u0 = *(uint2*)&QtS[r][c * 8];
        uint2 u1 = *(uint2*)&QtS[r][c * 8 + 4];
        *(uint4*)&Qt[(size_t)(b * NN + n0 + r) * CQ + c * 8] =
            make_uint4(u0.x, u0.y, u1.x, u1.y);
    }
}

// K2: row softmax stats via MFMA. Block: 64 rows, loop m. 4 waves x 16 rows.
__global__ __launch_bounds__(256) void k_rowstats(const ushort* __restrict__ Qt,
        float* __restrict__ RM, float* __restrict__ RS) {
    __shared__ ushort Qn[64][40];
    __shared__ ushort Qm[64][40];
    int b  = blockIdx.x >> 5;
    int n0 = (blockIdx.x & 31) << 6;
    int tid = threadIdx.x;
    {
        int r = tid >> 2, c = tid & 3;
        uint4 v = *(const uint4*)&Qt[(size_t)(b * NN + n0 + r) * CQ + c * 8];
        *(uint2*)&Qn[r][c * 8]     = make_uint2(v.x, v.y);
        *(uint2*)&Qn[r][c * 8 + 4] = make_uint2(v.z, v.w);
    }
    int w = tid >> 6, l = tid & 63, lr = l & 15, lg = l >> 4;
    float M[4], S[4];
    #pragma unroll
    for (int i = 0; i < 4; ++i) { M[i] = -1e30f; S[i] = 0.f; }
    f32x4 zero = {0.f, 0.f, 0.f, 0.f};
    for (int mt = 0; mt < NN; mt += 64) {
        __syncthreads();
        {
            int r = tid >> 2, c = tid & 3;
            uint4 v = *(const uint4*)&Qt[(size_t)(b * NN + mt + r) * CQ + c * 8];
            *(uint2*)&Qm[r][c * 8]     = make_uint2(v.x, v.y);
            *(uint2*)&Qm[r][c * 8 + 4] = make_uint2(v.z, v.w);
        }
        __syncthreads();
        bf16x8 a = *(bf16x8*)&Qn[w * 16 + lr][lg * 8];
        f32x4 e[4];
        #pragma unroll
        for (int mi = 0; mi < 4; ++mi) {
            bf16x8 bq = *(bf16x8*)&Qm[mi * 16 + lr][lg * 8];
            e[mi] = __builtin_amdgcn_mfma_f32_16x16x32_bf16(a, bq, zero, 0, 0, 0);
        }
        #pragma unroll
        for (int i = 0; i < 4; ++i) {
            float m4 = fmaxf(fmaxf(e[0][i], e[1][i]), fmaxf(e[2][i], e[3][i]));
            float nm = fmaxf(M[i], m4);
            float s4 = __expf(e[0][i] - nm) + __expf(e[1][i] - nm)
                     + __expf(e[2][i] - nm) + __expf(e[3][i] - nm);
            S[i] = S[i] * __expf(M[i] - nm) + s4;
            M[i] = nm;
        }
    }
    #pragma unroll
    for (int d = 1; d < 16; d <<= 1) {
        #pragma unroll
        for (int i = 0; i < 4; ++i) {
            float Mo = __shfl_xor(M[i], d);
            float So = __shfl_xor(S[i], d);
            float nm = fmaxf(M[i], Mo);
            S[i] = S[i] * __expf(M[i] - nm) + So * __expf(Mo - nm);
            M[i] = nm;
        }
    }
    if (lr == 0) {
        #pragma unroll
        for (int i = 0; i < 4; ++i) {
            int n = n0 + w * 16 + lg * 4 + i;
            RM[b * NN + n] = M[i];
            RS[b * NN + n] = S[i];
        }
    }
}

// K3: MFMA attn + PV. Block: m-tile 64, full d=128, loop n.
// E: waves split (n,m) 2x2.  PV: wave w owns d-strip [32w,32w+32).
__global__ __launch_bounds__(256) void k_attn_pv(const ushort* __restrict__ Qt,
        const ushort* __restrict__ Vb, const float* __restrict__ RM,
        const float* __restrict__ RS, float* __restrict__ XR) {
    __shared__ ushort Qm[64][40];    // [m][k]
    __shared__ ushort Qn[64][40];    // [n][k]
    __shared__ ushort Vs[128][72];   // [d][n]
    __shared__ ushort Ws[64][72];    // [m][n]
    __shared__ float rm_s[64], rsi_s[64];
    __shared__ float csred[2][64];
    int b  = blockIdx.x >> 5;
    int m0 = (blockIdx.x & 31) << 6;
    int tid = threadIdx.x;
    int w = tid >> 6, l = tid & 63, lr = l & 15, lg = l >> 4;
    int en = w >> 1, em = w & 1;
    {
        int r = tid >> 2, c = tid & 3;
        uint4 v = *(const uint4*)&Qt[(size_t)(b * NN + m0 + r) * CQ + c * 8];
        *(uint2*)&Qm[r][c * 8]     = make_uint2(v.x, v.y);
        *(uint2*)&Qm[r][c * 8 + 4] = make_uint2(v.z, v.w);
    }
    f32x4 zero = {0.f, 0.f, 0.f, 0.f};
    f32x4 pacc[2][4];
    #pragma unroll
    for (int di = 0; di < 2; ++di)
        for (int mi = 0; mi < 4; ++mi) pacc[di][mi] = zero;
    float cs0 = 0.f, cs1 = 0.f;
    for (int nt = 0; nt < NN; nt += 64) {
        __syncthreads();
        {
            int r = tid >> 2, c = tid & 3;
            uint4 v = *(const uint4*)&Qt[(size_t)(b * NN + nt + r) * CQ + c * 8];
            *(uint2*)&Qn[r][c * 8]     = make_uint2(v.x, v.y);
            *(uint2*)&Qn[r][c * 8 + 4] = make_uint2(v.z, v.w);
        }
        {
            int d = tid >> 1, h = tid & 1;
            const ushort* src = Vb + (size_t)(b * CC + d) * NN + nt + h * 32;
            #pragma unroll
            for (int j = 0; j < 4; ++j) {
                uint4 v = *(const uint4*)(src + j * 8);
                *(uint4*)&Vs[d][h * 32 + j * 8] = v;
            }
        }
        if (tid < 64) {
            rm_s[tid]  = RM[b * NN + nt + tid];
            rsi_s[tid] = 1.0f / RS[b * NN + nt + tid];
        }
        __syncthreads();
        // ---- E phase ----
        bf16x8 a0  = *(bf16x8*)&Qn[en * 32 + lr][lg * 8];
        bf16x8 a1  = *(bf16x8*)&Qn[en * 32 + 16 + lr][lg * 8];
        bf16x8 bq0 = *(bf16x8*)&Qm[em * 32 + lr][lg * 8];
        bf16x8 bq1 = *(bf16x8*)&Qm[em * 32 + 16 + lr][lg * 8];
        f32x4 e00 = __builtin_amdgcn_mfma_f32_16x16x32_bf16(a0, bq0, zero, 0, 0, 0);
        f32x4 e01 = __builtin_amdgcn_mfma_f32_16x16x32_bf16(a0, bq1, zero, 0, 0, 0);
        f32x4 e10 = __builtin_amdgcn_mfma_f32_16x16x32_bf16(a1, bq0, zero, 0, 0, 0);
        f32x4 e11 = __builtin_amdgcn_mfma_f32_16x16x32_bf16(a1, bq1, zero, 0, 0, 0);
        // ---- W = exp(E - rm)*rsi, write to Ws[m][n], accumulate colsums ----
        #pragma unroll
        for (int t = 0; t < 4; ++t) {
            int ni = t >> 1, mi = t & 1;
            f32x4 e = (t == 0) ? e00 : (t == 1) ? e01 : (t == 2) ? e10 : e11;
            int nb = en * 32 + ni * 16 + lg * 4;
            int ml = em * 32 + mi * 16 + lr;
            float w0 = __expf(e[0] - rm_s[nb + 0]) * rsi_s[nb + 0];
            float w1 = __expf(e[1] - rm_s[nb + 1]) * rsi_s[nb + 1];
            float w2 = __expf(e[2] - rm_s[nb + 2]) * rsi_s[nb + 2];
            float w3 = __expf(e[3] - rm_s[nb + 3]) * rsi_s[nb + 3];
            if (mi == 0) cs0 += w0 + w1 + w2 + w3; else cs1 += w0 + w1 + w2 + w3;
            *(ushort4*)&Ws[ml][nb] = make_ushort4(f2b(w0), f2b(w1), f2b(w2), f2b(w3));
        }
        __syncthreads();
        // ---- PV phase: wave w owns d in [32w, 32w+32) ----
        #pragma unroll
        for (int kk = 0; kk < 2; ++kk) {
            bf16x8 va0 = *(bf16x8*)&Vs[w * 32 + lr][kk * 32 + lg * 8];
            bf16x8 va1 = *(bf16x8*)&Vs[w * 32 + 16 + lr][kk * 32 + lg * 8];
            #pragma unroll
            for (int mi = 0; mi < 4; ++mi) {
                bf16x8 wb = *(bf16x8*)&Ws[mi * 16 + lr][kk * 32 + lg * 8];
                pacc[0][mi] = __builtin_amdgcn_mfma_f32_16x16x32_bf16(va0, wb, pacc[0][mi], 0, 0, 0);
                pacc[1][mi] = __builtin_amdgcn_mfma_f32_16x16x32_bf16(va1, wb, pacc[1][mi], 0, 0, 0);
            }
        }
    }
    // column-sum reduce: over lg groups (shfl) then across en (LDS)
    cs0 += __shfl_xor(cs0, 16); cs0 += __shfl_xor(cs0, 32);
    cs1 += __shfl_xor(cs1, 16); cs1 += __shfl_xor(cs1, 32);
    __syncthreads();
    if (l < 16) {
        csred[en][em * 32 + l]      = cs0;
        csred[en][em * 32 + 16 + l] = cs1;
    }
    __syncthreads();
    #pragma unroll
    for (int mi = 0; mi < 4; ++mi) {
        int ml = mi * 16 + lr;
        float inv = 1.0f / (1e-9f + csred[0][ml] + csred[1][ml]);
        #pragma unroll
        for (int di = 0; di < 2; ++di) {
            #pragma unroll
            for (int i = 0; i < 4; ++i) {
                int d = w * 32 + di * 16 + lg * 4 + i;
                XR[(size_t)(b * CC + d) * NN + m0 + ml] = pacc[di][mi][i] * inv;
            }
        }
    }
}

// K4: t = wt @ (x - XR) + bt ; BN eval + ReLU ; out = x + relu(t)
__global__ __launch_bounds__(256) void k_final(const float* __restrict__ x,
        const float* __restrict__ XR, const float* __restrict__ wt_t,
        const float* __restrict__ bt, const float* __restrict__ gamma,
        const float* __restrict__ beta, const float* __restrict__ bn_mean,
        const float* __restrict__ bn_var, float* __restrict__ out) {
    __shared__ float us[CC][68];
    int b  = blockIdx.x >> 5;
    int m0 = (blockIdx.x & 31) << 6;
    int tid = threadIdx.x;
    const float* xb  = x  + (size_t)b * CC * NN;
    const float* xrb = XR + (size_t)b * CC * NN;
    for (int idx = tid; idx < CC * 64; idx += 256) {
        int c = idx >> 6, n = idx & 63;
        us[c][n] = xb[c * NN + m0 + n] - xrb[c * NN + m0 + n];
    }
    __syncthreads();
    int c = tid & 127, h = tid >> 7;
    float acc[32];
    #pragma unroll
    for (int j = 0; j < 32; ++j) acc[j] = 0.f;
    for (int c2 = 0; c2 < CC; ++c2) {
        float w = wt_t[c2 * CC + c];
        #pragma unroll
        for (int j4 = 0; j4 < 32; j4 += 4) {
            float4 uv = *(const float4*)&us[c2][h * 32 + j4];
            acc[j4]     += w * uv.x;
            acc[j4 + 1] += w * uv.y;
            acc[j4 + 2] += w * uv.z;
            acc[j4 + 3] += w * uv.w;
        }
    }
    float A  = gamma[c] * rsqrtf(bn_var[c] + 1e-5f);
    float Bc = beta[c] - bn_mean[c] * A;
    float tb = bt[c];
    __syncthreads();
    #pragma unroll
    for (int j = 0; j < 32; ++j) {
        float t = (acc[j] + tb) * A + Bc;
        us[c][h * 32 + j] = fmaxf(t, 0.f);
    }
    __syncthreads();
    for (int idx = tid; idx < CC * 64; idx += 256) {
        int cc = idx >> 6, n = idx & 63;
        out[(size_t)(b * CC + cc) * NN + m0 + n] = xb[cc * NN + m0 + n] + us[cc][n];
    }
}

extern "C" void kernel_launch(void* const* d_in, const int* in_sizes, int n_in,
                              void* d_out, int out_size, void* d_ws, size_t ws_size,
                              hipStream_t stream) {
    const float* x       = (const float*)d_in[0];
    const float* wq      = (const float*)d_in[1];
    const float* wv      = (const float*)d_in[2];
    const float* bv      = (const float*)d_in[3];
    const float* wt      = (const float*)d_in[4];
    const float* bt      = (const float*)d_in[5];
    const float* gamma   = (const float*)d_in[6];
    const float* beta    = (const float*)d_in[7];
    const float* bn_mean = (const float*)d_in[8];
    const float* bn_var  = (const float*)d_in[9];
    float* out = (float*)d_out;
    float* ws  = (float*)d_ws;

    ushort* Qt  = (ushort*)ws;
    ushort* Vbp = (ushort*)(ws + OFF_VB);
    float* XR   = ws + OFF_XR;
    float* RM   = ws + OFF_RM;
    float* RS   = ws + OFF_RS;
    float* WT_T = ws + OFF_WTT;

    k_wtT<<<64, 256, 0, stream>>>(wt, WT_T);
    k_proj<<<BB * 32, 256, 0, stream>>>(x, wq, wv, bv, Qt, Vbp);
    k_rowstats<<<BB * 32, 256, 0, stream>>>(Qt, RM, RS);
    k_attn_pv<<<BB * 32, 256, 0, stream>>>(Qt, Vbp, RM, RS, XR);
    k_final<<<BB * 32, 256, 0, stream>>>(x, XR, WT_T, bt, gamma, beta, bn_mean, bn_var, out);
}

// Round 3
// 124.746 us; speedup vs baseline: 5.6382x; 1.4232x over previous
//
#include <hip/hip_runtime.h>
#include <math.h>

#define BB 16
#define CC 128
#define NN 2048
#define CQ 32   // C/4

typedef __attribute__((ext_vector_type(8))) short bf16x8;
typedef __attribute__((ext_vector_type(4))) float f32x4;

__device__ __forceinline__ ushort f2b(float f) {
    union { float f; unsigned u; } v; v.f = f;
    unsigned r = v.u + 0x7fffu + ((v.u >> 16) & 1u);
    return (ushort)(r >> 16);
}
__device__ __forceinline__ float b2f(ushort u) {
    union { unsigned u; float f; } v; v.u = ((unsigned)u) << 16;
    return v.f;
}

// ---------------- workspace layout (float granularity offsets) ----------------
// Qt   : bf16 [B][N][32]    off 0          (524,288 fl)
// Vb   : bf16 [B][128][N]   off 524,288    (2,097,152 fl)
// XRb  : bf16 [B][128][N]   off 2,621,440  (2,097,152 fl)
// RM   : f32  [B][N]        off 4,718,592
// RS   : f32  [B][N]        off 4,751,360
// WQV  : bf16 [160][128]    off 4,784,128  (10,240 fl)  rows 0-31 wq, 32-159 wv
// WTB  : bf16 [128][128]    off 4,794,368  (8,192 fl)
// FA   : f32  [128]         off 4,802,560
// FB   : f32  [128]         off 4,802,688
#define OFF_VB  524288
#define OFF_XRB 2621440
#define OFF_RM  4718592
#define OFF_RS  4751360
#define OFF_WQV 4784128
#define OFF_WTB 4794368
#define OFF_FA  4802560
#define OFF_FB  4802688

// K0: cast weights to bf16 + fold BN constants
__global__ void k_wprep(const float* __restrict__ wq, const float* __restrict__ wv,
        const float* __restrict__ wt, const float* __restrict__ bt,
        const float* __restrict__ gamma, const float* __restrict__ beta,
        const float* __restrict__ bn_mean, const float* __restrict__ bn_var,
        ushort* __restrict__ wqvb, ushort* __restrict__ wtb,
        float* __restrict__ fA, float* __restrict__ fB) {
    int idx = blockIdx.x * 256 + threadIdx.x;
    if (idx < 4096) wqvb[idx] = f2b(wq[idx]);
    else if (idx < 20480) wqvb[idx] = f2b(wv[idx - 4096]);
    else if (idx < 36864) wtb[idx - 20480] = f2b(wt[idx - 20480]);
    else if (idx < 36992) {
        int c = idx - 36864;
        float A = gamma[c] * rsqrtf(bn_var[c] + 1e-5f);
        fA[c] = A;
        fB[c] = (bt[c] - bn_mean[c]) * A + beta[c];
    }
}

// K1: MFMA projection.  Qt[b,n,d] (d<32), Vb[b,d,n] = wv.x + bv.
__global__ __launch_bounds__(256) void k_proj(const float* __restrict__ x,
        const ushort* __restrict__ wqvb, const float* __restrict__ bv,
        ushort* __restrict__ Qt, ushort* __restrict__ Vb) {
    __shared__ ushort Xs[64][136];   // [n][c] bf16
    int b  = blockIdx.x >> 5;
    int n0 = (blockIdx.x & 31) << 6;
    int tid = threadIdx.x;
    const float* xb = x + (size_t)b * CC * NN;
    for (int idx = tid; idx < 2048; idx += 256) {
        int c = idx >> 4, n4 = (idx & 15) << 2;
        float4 xv = *(const float4*)&xb[c * NN + n0 + n4];
        Xs[n4][c]     = f2b(xv.x);
        Xs[n4 + 1][c] = f2b(xv.y);
        Xs[n4 + 2][c] = f2b(xv.z);
        Xs[n4 + 3][c] = f2b(xv.w);
    }
    __syncthreads();
    int w = tid >> 6, l = tid & 63, lr = l & 15, lg = l >> 4;
    f32x4 zero = {0.f, 0.f, 0.f, 0.f};
    int nn = n0 + w * 16 + lr;
    for (int dt = 0; dt < 10; ++dt) {
        f32x4 acc = zero;
        #pragma unroll
        for (int k = 0; k < 4; ++k) {
            bf16x8 a  = *(const bf16x8*)&wqvb[(dt * 16 + lr) * 128 + k * 32 + lg * 8];
            bf16x8 bx = *(const bf16x8*)&Xs[w * 16 + lr][k * 32 + lg * 8];
            acc = __builtin_amdgcn_mfma_f32_16x16x32_bf16(a, bx, acc, 0, 0, 0);
        }
        if (dt < 2) {
            ushort4 p = make_ushort4(f2b(acc[0]), f2b(acc[1]), f2b(acc[2]), f2b(acc[3]));
            *(ushort4*)&Qt[(size_t)(b * NN + nn) * CQ + dt * 16 + lg * 4] = p;
        } else {
            #pragma unroll
            for (int i = 0; i < 4; ++i) {
                int vd = (dt - 2) * 16 + lg * 4 + i;
                Vb[(size_t)(b * CC + vd) * NN + nn] = f2b(acc[i] + bv[vd]);
            }
        }
    }
}

// K2: row softmax stats via MFMA (unchanged from R2).
__global__ __launch_bounds__(256) void k_rowstats(const ushort* __restrict__ Qt,
        float* __restrict__ RM, float* __restrict__ RS) {
    __shared__ ushort Qn[64][40];
    __shared__ ushort Qm[64][40];
    int b  = blockIdx.x >> 5;
    int n0 = (blockIdx.x & 31) << 6;
    int tid = threadIdx.x;
    {
        int r = tid >> 2, c = tid & 3;
        uint4 v = *(const uint4*)&Qt[(size_t)(b * NN + n0 + r) * CQ + c * 8];
        *(uint2*)&Qn[r][c * 8]     = make_uint2(v.x, v.y);
        *(uint2*)&Qn[r][c * 8 + 4] = make_uint2(v.z, v.w);
    }
    int w = tid >> 6, l = tid & 63, lr = l & 15, lg = l >> 4;
    float M[4], S[4];
    #pragma unroll
    for (int i = 0; i < 4; ++i) { M[i] = -1e30f; S[i] = 0.f; }
    f32x4 zero = {0.f, 0.f, 0.f, 0.f};
    for (int mt = 0; mt < NN; mt += 64) {
        __syncthreads();
        {
            int r = tid >> 2, c = tid & 3;
            uint4 v = *(const uint4*)&Qt[(size_t)(b * NN + mt + r) * CQ + c * 8];
            *(uint2*)&Qm[r][c * 8]     = make_uint2(v.x, v.y);
            *(uint2*)&Qm[r][c * 8 + 4] = make_uint2(v.z, v.w);
        }
        __syncthreads();
        bf16x8 a = *(bf16x8*)&Qn[w * 16 + lr][lg * 8];
        f32x4 e[4];
        #pragma unroll
        for (int mi = 0; mi < 4; ++mi) {
            bf16x8 bq = *(bf16x8*)&Qm[mi * 16 + lr][lg * 8];
            e[mi] = __builtin_amdgcn_mfma_f32_16x16x32_bf16(a, bq, zero, 0, 0, 0);
        }
        #pragma unroll
        for (int i = 0; i < 4; ++i) {
            float m4 = fmaxf(fmaxf(e[0][i], e[1][i]), fmaxf(e[2][i], e[3][i]));
            float nm = fmaxf(M[i], m4);
            float s4 = __expf(e[0][i] - nm) + __expf(e[1][i] - nm)
                     + __expf(e[2][i] - nm) + __expf(e[3][i] - nm);
            S[i] = S[i] * __expf(M[i] - nm) + s4;
            M[i] = nm;
        }
    }
    #pragma unroll
    for (int d = 1; d < 16; d <<= 1) {
        #pragma unroll
        for (int i = 0; i < 4; ++i) {
            float Mo = __shfl_xor(M[i], d);
            float So = __shfl_xor(S[i], d);
            float nm = fmaxf(M[i], Mo);
            S[i] = S[i] * __expf(M[i] - nm) + So * __expf(Mo - nm);
            M[i] = nm;
        }
    }
    if (lr == 0) {
        #pragma unroll
        for (int i = 0; i < 4; ++i) {
            int n = n0 + w * 16 + lg * 4 + i;
            RM[b * NN + n] = M[i];
            RS[b * NN + n] = S[i];
        }
    }
}

// K3: MFMA attn + PV, 8 waves. E: wave=(n-tile w&3, m-tiles 2*(w>>2)+{0,1}).
// PV: wave w owns d-rows [16w,16w+16). Output XRb bf16 [d][m].
__global__ __launch_bounds__(512) void k_attn_pv(const ushort* __restrict__ Qt,
        const ushort* __restrict__ Vb, const float* __restrict__ RM,
        const float* __restrict__ RS, ushort* __restrict__ XRb) {
    __shared__ ushort Qm[64][40];    // [m][k]
    __shared__ ushort Qn[64][40];    // [n][k]
    __shared__ ushort Vs[128][72];   // [d][n]
    __shared__ ushort Ws[64][72];    // [m][n]
    __shared__ float rm_s[64], rsi_s[64];
    __shared__ float csred[4][64];
    int b  = blockIdx.x >> 5;
    int m0 = (blockIdx.x & 31) << 6;
    int tid = threadIdx.x;
    int w = tid >> 6, l = tid & 63, lr = l & 15, lg = l >> 4;
    int wn = w & 3, wm = w >> 2;
    {
        int r = tid >> 3, c = tid & 7;
        *(uint2*)&Qm[r][c * 4] = *(const uint2*)&Qt[(size_t)(b * NN + m0 + r) * CQ + c * 4];
    }
    f32x4 zero = {0.f, 0.f, 0.f, 0.f};
    f32x4 pacc[4];
    #pragma unroll
    for (int mi = 0; mi < 4; ++mi) pacc[mi] = zero;
    float cs0 = 0.f, cs1 = 0.f;
    for (int nt = 0; nt < NN; nt += 64) {
        __syncthreads();
        {
            int r = tid >> 3, c = tid & 7;
            *(uint2*)&Qn[r][c * 4] = *(const uint2*)&Qt[(size_t)(b * NN + nt + r) * CQ + c * 4];
        }
        {
            int d = tid >> 2, h = tid & 3;
            const ushort* src = Vb + (size_t)(b * CC + d) * NN + nt + h * 16;
            *(uint4*)&Vs[d][h * 16]     = *(const uint4*)(src);
            *(uint4*)&Vs[d][h * 16 + 8] = *(const uint4*)(src + 8);
        }
        if (tid < 64) {
            rm_s[tid]  = RM[b * NN + nt + tid];
            rsi_s[tid] = 1.0f / RS[b * NN + nt + tid];
        }
        __syncthreads();
        // ---- E phase: 2 MFMAs per wave ----
        bf16x8 a  = *(bf16x8*)&Qn[wn * 16 + lr][lg * 8];
        bf16x8 b0 = *(bf16x8*)&Qm[wm * 32 + lr][lg * 8];
        bf16x8 b1 = *(bf16x8*)&Qm[wm * 32 + 16 + lr][lg * 8];
        f32x4 e0 = __builtin_amdgcn_mfma_f32_16x16x32_bf16(a, b0, zero, 0, 0, 0);
        f32x4 e1 = __builtin_amdgcn_mfma_f32_16x16x32_bf16(a, b1, zero, 0, 0, 0);
        int nb = wn * 16 + lg * 4;
        float r0 = rm_s[nb], r1 = rm_s[nb + 1], r2 = rm_s[nb + 2], r3 = rm_s[nb + 3];
        float s0 = rsi_s[nb], s1 = rsi_s[nb + 1], s2 = rsi_s[nb + 2], s3 = rsi_s[nb + 3];
        {
            float w0 = __expf(e0[0] - r0) * s0;
            float w1 = __expf(e0[1] - r1) * s1;
            float w2 = __expf(e0[2] - r2) * s2;
            float w3 = __expf(e0[3] - r3) * s3;
            cs0 += w0 + w1 + w2 + w3;
            *(ushort4*)&Ws[wm * 32 + lr][nb] = make_ushort4(f2b(w0), f2b(w1), f2b(w2), f2b(w3));
        }
        {
            float w0 = __expf(e1[0] - r0) * s0;
            float w1 = __expf(e1[1] - r1) * s1;
            float w2 = __expf(e1[2] - r2) * s2;
            float w3 = __expf(e1[3] - r3) * s3;
            cs1 += w0 + w1 + w2 + w3;
            *(ushort4*)&Ws[wm * 32 + 16 + lr][nb] = make_ushort4(f2b(w0), f2b(w1), f2b(w2), f2b(w3));
        }
        __syncthreads();
        // ---- PV: wave w owns d in [16w, 16w+16) ----
        #pragma unroll
        for (int kk = 0; kk < 2; ++kk) {
            bf16x8 va = *(bf16x8*)&Vs[w * 16 + lr][kk * 32 + lg * 8];
            #pragma unroll
            for (int mi = 0; mi < 4; ++mi) {
                bf16x8 wb = *(bf16x8*)&Ws[mi * 16 + lr][kk * 32 + lg * 8];
                pacc[mi] = __builtin_amdgcn_mfma_f32_16x16x32_bf16(va, wb, pacc[mi], 0, 0, 0);
            }
        }
    }
    // column sums: reduce over lg (shfl), then over n-tiles (LDS)
    cs0 += __shfl_xor(cs0, 16); cs0 += __shfl_xor(cs0, 32);
    cs1 += __shfl_xor(cs1, 16); cs1 += __shfl_xor(cs1, 32);
    __syncthreads();
    if (lg == 0) {
        csred[wn][wm * 32 + lr]      = cs0;
        csred[wn][wm * 32 + 16 + lr] = cs1;
    }
    __syncthreads();
    #pragma unroll
    for (int mi = 0; mi < 4; ++mi) {
        int ml = mi * 16 + lr;
        float inv = 1.0f / (1e-9f + csred[0][ml] + csred[1][ml] + csred[2][ml] + csred[3][ml]);
        #pragma unroll
        for (int i = 0; i < 4; ++i) {
            int d = w * 16 + lg * 4 + i;
            XRb[(size_t)(b * CC + d) * NN + m0 + ml] = f2b(pacc[mi][i] * inv);
        }
    }
}

// K4: MFMA final: t = wtb @ (x - XR); out = x + relu(t*fA + fB)
__global__ __launch_bounds__(256) void k_final(const float* __restrict__ x,
        const ushort* __restrict__ XRb, const ushort* __restrict__ wtb,
        const float* __restrict__ fA, const float* __restrict__ fB,
        float* __restrict__ out) {
    __shared__ ushort Us[64][136];   // [n][c] bf16
    int b  = blockIdx.x >> 5;
    int n0 = (blockIdx.x & 31) << 6;
    int tid = threadIdx.x;
    const float*  xb  = x   + (size_t)b * CC * NN;
    const ushort* xrb = XRb + (size_t)b * CC * NN;
    for (int idx = tid; idx < 2048; idx += 256) {
        int c = idx >> 4, n4 = (idx & 15) << 2;
        float4 xv = *(const float4*)&xb[c * NN + n0 + n4];
        ushort4 rv = *(const ushort4*)&xrb[c * NN + n0 + n4];
        Us[n4][c]     = f2b(xv.x - b2f(rv.x));
        Us[n4 + 1][c] = f2b(xv.y - b2f(rv.y));
        Us[n4 + 2][c] = f2b(xv.z - b2f(rv.z));
        Us[n4 + 3][c] = f2b(xv.w - b2f(rv.w));
    }
    __syncthreads();
    int w = tid >> 6, l = tid & 63, lr = l & 15, lg = l >> 4;
    f32x4 zero = {0.f, 0.f, 0.f, 0.f};
    int nn = n0 + w * 16 + lr;
    for (int dt = 0; dt < 8; ++dt) {
        f32x4 acc = zero;
        #pragma unroll
        for (int k = 0; k < 4; ++k) {
            bf16x8 a  = *(const bf16x8*)&wtb[(dt * 16 + lr) * 128 + k * 32 + lg * 8];
            bf16x8 bx = *(const bf16x8*)&Us[w * 16 + lr][k * 32 + lg * 8];
            acc = __builtin_amdgcn_mfma_f32_16x16x32_bf16(a, bx, acc, 0, 0, 0);
        }
        #pragma unroll
        for (int i = 0; i < 4; ++i) {
            int r = dt * 16 + lg * 4 + i;
            float t = acc[i] * fA[r] + fB[r];
            t = fmaxf(t, 0.f);
            out[(size_t)(b * CC + r) * NN + nn] = xb[r * NN + nn] + t;
        }
    }
}

extern "C" void kernel_launch(void* const* d_in, const int* in_sizes, int n_in,
                              void* d_out, int out_size, void* d_ws, size_t ws_size,
                              hipStream_t stream) {
    const float* x       = (const float*)d_in[0];
    const float* wq      = (const float*)d_in[1];
    const float* wv      = (const float*)d_in[2];
    const float* bv      = (const float*)d_in[3];
    const float* wt      = (const float*)d_in[4];
    const float* bt      = (const float*)d_in[5];
    const float* gamma   = (const float*)d_in[6];
    const float* beta    = (const float*)d_in[7];
    const float* bn_mean = (const float*)d_in[8];
    const float* bn_var  = (const float*)d_in[9];
    float* out = (float*)d_out;
    float* ws  = (float*)d_ws;

    ushort* Qt   = (ushort*)ws;
    ushort* Vbp  = (ushort*)(ws + OFF_VB);
    ushort* XRb  = (ushort*)(ws + OFF_XRB);
    float*  RM   = ws + OFF_RM;
    float*  RS   = ws + OFF_RS;
    ushort* WQV  = (ushort*)(ws + OFF_WQV);
    ushort* WTB  = (ushort*)(ws + OFF_WTB);
    float*  FA   = ws + OFF_FA;
    float*  FB   = ws + OFF_FB;

    k_wprep<<<145, 256, 0, stream>>>(wq, wv, wt, bt, gamma, beta, bn_mean, bn_var,
                                     WQV, WTB, FA, FB);
    k_proj<<<BB * 32, 256, 0, stream>>>(x, WQV, bv, Qt, Vbp);
    k_rowstats<<<BB * 32, 256, 0, stream>>>(Qt, RM, RS);
    k_attn_pv<<<BB * 32, 512, 0, stream>>>(Qt, Vbp, RM, RS, XRb);
    k_final<<<BB * 32, 256, 0, stream>>>(x, XRb, WTB, FA, FB, out);
}